// Round 5
// baseline (338.915 us; speedup 1.0000x reference)
//
#include <hip/hip_runtime.h>
#include <hip/hip_bf16.h>

// ParallelMHA: B=2, N=2048, D=1024, H=16, HD=64. fp32 in/out, bf16 MFMA compute.
// Pipeline: converts -> QKV GEMM (gload_lds staging; Q*log2e/8, V transposed)
//           -> flash attn (fixed-max softmax, K-split x2 + merge) -> O GEMM

typedef __bf16 bf16;
typedef __bf16 bf16x4 __attribute__((ext_vector_type(4)));
typedef __bf16 bf16x8 __attribute__((ext_vector_type(8)));
typedef float f32x4 __attribute__((ext_vector_type(4)));

__device__ __forceinline__ f32x4 mfma16(bf16x8 a, bf16x8 b, f32x4 c) {
    return __builtin_amdgcn_mfma_f32_16x16x32_bf16(a, b, c, 0, 0, 0);
}

__device__ __forceinline__ void gload16(const bf16* g, bf16* l) {
    __builtin_amdgcn_global_load_lds(
        (const __attribute__((address_space(1))) unsigned int*)g,
        (__attribute__((address_space(3))) unsigned int*)l, 16, 0, 0);
}

// ---------------- fp32 -> bf16 converts ----------------
__global__ __launch_bounds__(256) void f2b_kernel(const float* __restrict__ in,
                                                  bf16* __restrict__ out, int n) {
    int i = (blockIdx.x * 256 + threadIdx.x) * 4;
    if (i >= n) return;
    float4 v = *(const float4*)&in[i];
    bf16x4 o;
    o.x = (bf16)v.x; o.y = (bf16)v.y; o.z = (bf16)v.z; o.w = (bf16)v.w;
    *(bf16x4*)&out[i] = o;
}

// all four 1024x1024 weights in one launch: 4096 blocks, 1024 per matrix
__global__ __launch_bounds__(256) void w2b_kernel(
    const float* __restrict__ w0, const float* __restrict__ w1,
    const float* __restrict__ w2, const float* __restrict__ w3,
    bf16* __restrict__ o0, bf16* __restrict__ o1,
    bf16* __restrict__ o2, bf16* __restrict__ o3) {
    int sel = blockIdx.x >> 10;
    const float* in = sel == 0 ? w0 : sel == 1 ? w1 : sel == 2 ? w2 : w3;
    bf16* out = sel == 0 ? o0 : sel == 1 ? o1 : sel == 2 ? o2 : o3;
    int i = ((blockIdx.x & 1023) * 256 + threadIdx.x) * 4;
    float4 v = *(const float4*)&in[i];
    bf16x4 o;
    o.x = (bf16)v.x; o.y = (bf16)v.y; o.z = (bf16)v.z; o.w = (bf16)v.w;
    *(bf16x4*)&out[i] = o;
}

// ---------------- 128x128 bf16 GEMM, global_load_lds staging (m97 structure) -------
// C = A[M,K] @ B[N,K]^T. MODE 0: bf16 out *scale. MODE 1: f32 out + bias.
// MODE 2: bf16 out transposed (C[col][row], ld ldt).
template <int MODE>
__device__ __forceinline__ void gemm_body(const bf16* __restrict__ A,
                                          const bf16* __restrict__ B,
                                          bf16* __restrict__ Cb,
                                          float* __restrict__ Cf,
                                          const float* __restrict__ bias,
                                          float scale, int N, int K, int row0, int col0,
                                          int ldt) {
    __shared__ alignas(16) bf16 sA[128 * 32];
    __shared__ alignas(16) bf16 sB[128 * 32];
    const int tid  = threadIdx.x;
    const int lane = tid & 63;
    const int wave = tid >> 6;
    const int wrow = (wave >> 1) * 64;
    const int wcol = (wave & 1) * 64;
    const int la = lane & 15, lb = lane >> 4;

    const f32x4 fzero = {0.f, 0.f, 0.f, 0.f};
    f32x4 acc[4][4];
#pragma unroll
    for (int m = 0; m < 4; ++m)
#pragma unroll
        for (int n = 0; n < 4; ++n) acc[m][n] = fzero;

    for (int k0 = 0; k0 < K; k0 += 32) {
        // async global -> LDS staging, 16B/lane, layout linear in tid
#pragma unroll
        for (int i = 0; i < 2; ++i) {
            int idx = i * 256 + tid;
            int r = idx >> 2, s = idx & 3;
            gload16(&A[(size_t)(row0 + r) * K + k0 + s * 8], &sA[idx * 8]);
            gload16(&B[(size_t)(col0 + r) * K + k0 + s * 8], &sB[idx * 8]);
        }
        __syncthreads();
        bf16x8 af[4], bfv[4];
#pragma unroll
        for (int m = 0; m < 4; ++m)
            af[m] = *(const bf16x8*)&sA[(wrow + m * 16 + la) * 32 + lb * 8];
#pragma unroll
        for (int n = 0; n < 4; ++n)
            bfv[n] = *(const bf16x8*)&sB[(wcol + n * 16 + la) * 32 + lb * 8];
#pragma unroll
        for (int m = 0; m < 4; ++m)
#pragma unroll
            for (int n = 0; n < 4; ++n)
                acc[m][n] = mfma16(af[m], bfv[n], acc[m][n]);
        __syncthreads();
    }
#pragma unroll
    for (int m = 0; m < 4; ++m)
#pragma unroll
        for (int n = 0; n < 4; ++n) {
            int col = col0 + wcol + n * 16 + la;
            if (MODE == 2) {
                bf16x4 o4;
#pragma unroll
                for (int r = 0; r < 4; ++r) o4[r] = (bf16)acc[m][n][r];
                *(bf16x4*)&Cb[(size_t)col * ldt + row0 + wrow + m * 16 + lb * 4] = o4;
            } else {
#pragma unroll
                for (int r = 0; r < 4; ++r) {
                    int row = row0 + wrow + m * 16 + lb * 4 + r;
                    if (MODE == 1)
                        Cf[(size_t)row * N + col] = acc[m][n][r] + bias[col];
                    else
                        Cb[(size_t)row * N + col] = (bf16)(acc[m][n][r] * scale);
                }
            }
        }
}

__global__ __launch_bounds__(256) void gemm_qkv_kernel(
    const bf16* __restrict__ xb, const bf16* __restrict__ wq,
    const bf16* __restrict__ wk, const bf16* __restrict__ wv,
    bf16* __restrict__ Q, bf16* __restrict__ Kb, bf16* __restrict__ Vt) {
    int z = blockIdx.z;
    if (z == 2) {
        gemm_body<2>(xb, wv, Vt, nullptr, nullptr, 1.f, 1024, 1024,
                     blockIdx.x * 128, blockIdx.y * 128, 4096);
    } else {
        // Q scale = log2(e)/8 (exp2-based softmax); K scale = 1
        gemm_body<0>(xb, z ? wk : wq, z ? Kb : Q, nullptr, nullptr,
                     z ? 1.0f : 0.1803368801111204f, 1024, 1024,
                     blockIdx.x * 128, blockIdx.y * 128, 0);
    }
}

__global__ __launch_bounds__(256) void gemm_out_kernel(
    const bf16* __restrict__ att, const bf16* __restrict__ wo,
    float* __restrict__ out, const float* __restrict__ bias) {
    gemm_body<1>(att, wo, nullptr, out, bias, 1.f, 1024, 1024,
                 blockIdx.x * 128, blockIdx.y * 128, 0);
}

// ---------------- flash attention (causal), fixed-max softmax, K-split ----------------
// Q/K/O: [b*2048+n][h*64+hd] (ld 1024); Vt: [h*64+hd][b*2048+n] (ld 4096).
// 4 independent waves/block, 32 q-rows/wave, KBLK=64. p = exp2(s - 10*log2e).
// SPLITS==2: blockIdx.z halves each wave's tile range; partials additive (fixed max).
struct KF { bf16x8 f[4][2]; };

template <int SPLITS>
__global__ __launch_bounds__(256, 4) void attn_kernel(
    const bf16* __restrict__ Q, const bf16* __restrict__ K,
    const bf16* __restrict__ Vt, bf16* __restrict__ O,
    bf16* __restrict__ Opart, float* __restrict__ Lpart) {
    __shared__ alignas(16) char Plds[4][4096];  // per-wave P[32][64] bf16, XOR-swizzled
    const int lane = threadIdx.x & 63;
    const int wave = threadIdx.x >> 6;
    const int slot = blockIdx.y;
    const int qt = slot < 8 ? slot : 23 - slot;  // long+short pairing
    const int h = blockIdx.x & 15;
    const int b = blockIdx.x >> 4;
    const int split = (SPLITS == 2) ? blockIdx.z : 0;
    const int q0w = qt * 128 + wave * 32;
    const int rowbase = b * 2048;
    const int colbase = h * 64;
    const int la = lane & 15, lb = lane >> 4;
    const f32x4 fzero = {0.f, 0.f, 0.f, 0.f};
    char* pbase = Plds[wave];
    const float C = 14.426950408889634f;  // 10 * log2(e)

    bf16x8 aq[2][2];
#pragma unroll
    for (int mf = 0; mf < 2; ++mf) {
        const bf16* qp = &Q[(size_t)(rowbase + q0w + mf * 16 + la) * 1024 + colbase];
#pragma unroll
        for (int kc = 0; kc < 2; ++kc) aq[mf][kc] = *(const bf16x8*)(qp + kc * 32 + lb * 8);
    }

    bf16x8 bones;
#pragma unroll
    for (int j = 0; j < 8; ++j) bones[j] = (bf16)1.0f;

    f32x4 o[2][4], lacc[2];
#pragma unroll
    for (int mf = 0; mf < 2; ++mf) {
        lacc[mf] = fzero;
#pragma unroll
        for (int hc = 0; hc < 4; ++hc) o[mf][hc] = fzero;
    }

    const int nt = (q0w + 95) >> 6;  // causal trip count for this wave
    int t0 = 0, t1 = nt;
    if (SPLITS == 2) {
        int half = nt >> 1;
        t0 = split ? half : 0;
        t1 = split ? nt : half;
    }

    KF ka, kb;
    if (t0 < t1) {
#pragma unroll
        for (int ck = 0; ck < 4; ++ck) {
            const bf16* kp = &K[(size_t)(rowbase + t0 * 64 + ck * 16 + la) * 1024 + colbase];
            ka.f[ck][0] = *(const bf16x8*)(kp + lb * 8);
            ka.f[ck][1] = *(const bf16x8*)(kp + 32 + lb * 8);
        }
    }

    auto TILE = [&](int tile, KF& kc, KF& kn, int pref) {
        const int k0 = tile * 64;
        const bool domask = (tile == nt - 1);
        // V loads for this tile
        bf16x8 bv[4][2];
#pragma unroll
        for (int hc = 0; hc < 4; ++hc) {
            const bf16* vp = &Vt[(size_t)(colbase + hc * 16 + la) * 4096 + rowbase + k0];
            bv[hc][0] = *(const bf16x8*)(vp + lb * 8);
            bv[hc][1] = *(const bf16x8*)(vp + 32 + lb * 8);
        }
        // K prefetch for next tile
#pragma unroll
        for (int ck = 0; ck < 4; ++ck) {
            const bf16* kp = &K[(size_t)(rowbase + pref * 64 + ck * 16 + la) * 1024 + colbase];
            kn.f[ck][0] = *(const bf16x8*)(kp + lb * 8);
            kn.f[ck][1] = *(const bf16x8*)(kp + 32 + lb * 8);
        }
        // S = Q @ K^T
        f32x4 s[2][4];
#pragma unroll
        for (int mf = 0; mf < 2; ++mf)
#pragma unroll
            for (int ck = 0; ck < 4; ++ck) s[mf][ck] = fzero;
        __builtin_amdgcn_s_setprio(1);
#pragma unroll
        for (int ck = 0; ck < 4; ++ck)
#pragma unroll
            for (int mf = 0; mf < 2; ++mf) {
                s[mf][ck] = mfma16(aq[mf][0], kc.f[ck][0], s[mf][ck]);
                s[mf][ck] = mfma16(aq[mf][1], kc.f[ck][1], s[mf][ck]);
            }
        __builtin_amdgcn_s_setprio(0);
        if (domask) {
#pragma unroll
            for (int mf = 0; mf < 2; ++mf)
#pragma unroll
                for (int ck = 0; ck < 4; ++ck) {
                    int key = k0 + ck * 16 + la;
#pragma unroll
                    for (int r = 0; r < 4; ++r) {
                        int qrow = q0w + mf * 16 + lb * 4 + r;
                        if (key > qrow) s[mf][ck][r] = -1e30f;
                    }
                }
        }
        // P = exp2(s - C) -> swizzled LDS (transpose to A-operand layout)
#pragma unroll
        for (int mf = 0; mf < 2; ++mf)
#pragma unroll
            for (int ck = 0; ck < 4; ++ck)
#pragma unroll
                for (int r = 0; r < 4; ++r) {
                    float p = __builtin_amdgcn_exp2f(s[mf][ck][r] - C);
                    int row = mf * 16 + lb * 4 + r;
                    int cb = (ck * 16 + la) * 2;
                    *(bf16*)(pbase + row * 128 + (cb ^ ((row & 7) << 4))) = (bf16)p;
                }
        __builtin_amdgcn_wave_barrier();
        bf16x8 pa[2][2];
#pragma unroll
        for (int mf = 0; mf < 2; ++mf)
#pragma unroll
            for (int kc2 = 0; kc2 < 2; ++kc2) {
                int row = mf * 16 + la;
                int cb = kc2 * 64 + lb * 16;
                pa[mf][kc2] =
                    *(const bf16x8*)(pbase + row * 128 + (cb ^ ((row & 7) << 4)));
            }
        // PV + l-sum via ones
        __builtin_amdgcn_s_setprio(1);
#pragma unroll
        for (int hc = 0; hc < 4; ++hc)
#pragma unroll
            for (int mf = 0; mf < 2; ++mf) {
                o[mf][hc] = mfma16(pa[mf][0], bv[hc][0], o[mf][hc]);
                o[mf][hc] = mfma16(pa[mf][1], bv[hc][1], o[mf][hc]);
            }
#pragma unroll
        for (int mf = 0; mf < 2; ++mf) {
            lacc[mf] = mfma16(pa[mf][0], bones, lacc[mf]);
            lacc[mf] = mfma16(pa[mf][1], bones, lacc[mf]);
        }
        __builtin_amdgcn_s_setprio(0);
        __builtin_amdgcn_wave_barrier();
    };

    int t = t0;
    for (; t + 2 <= t1; t += 2) {
        TILE(t, ka, kb, t + 1);
        TILE(t + 1, kb, ka, (t + 2 < t1 ? t + 2 : t1 - 1));
    }
    if (t < t1) TILE(t, ka, kb, t1 - 1);

    // epilogue
    if (SPLITS == 2) {
        bf16* op = Opart + (size_t)split * 4096 * 1024;
#pragma unroll
        for (int mf = 0; mf < 2; ++mf)
#pragma unroll
            for (int hc = 0; hc < 4; ++hc)
#pragma unroll
                for (int r = 0; r < 4; ++r) {
                    int qrow = q0w + mf * 16 + lb * 4 + r;
                    op[(size_t)(rowbase + qrow) * 1024 + colbase + hc * 16 + la] =
                        (bf16)o[mf][hc][r];
                }
        if (la == 0) {
#pragma unroll
            for (int mf = 0; mf < 2; ++mf)
#pragma unroll
                for (int r = 0; r < 4; ++r) {
                    int qrow = q0w + mf * 16 + lb * 4 + r;
                    Lpart[(size_t)split * 4096 * 16 + (size_t)(rowbase + qrow) * 16 + h] =
                        lacc[mf][r];
                }
        }
    } else {
#pragma unroll
        for (int mf = 0; mf < 2; ++mf)
#pragma unroll
            for (int hc = 0; hc < 4; ++hc)
#pragma unroll
                for (int r = 0; r < 4; ++r) {
                    int qrow = q0w + mf * 16 + lb * 4 + r;
                    O[(size_t)(rowbase + qrow) * 1024 + colbase + hc * 16 + la] =
                        (bf16)(o[mf][hc][r] / lacc[mf][r]);
                }
    }
}

__global__ __launch_bounds__(256) void attn_merge_kernel(
    const bf16* __restrict__ Opart, const float* __restrict__ Lpart,
    bf16* __restrict__ O) {
    int i = (blockIdx.x * 256 + threadIdx.x) * 4;
    int row = i >> 10, c = i & 1023, h = c >> 6;
    float l0 = Lpart[row * 16 + h];
    float l1 = Lpart[4096 * 16 + row * 16 + h];
    float rl = 1.f / (l0 + l1);
    bf16x4 a = *(const bf16x4*)&Opart[i];
    bf16x4 b2 = *(const bf16x4*)&Opart[(size_t)4096 * 1024 + i];
    bf16x4 o;
#pragma unroll
    for (int j = 0; j < 4; ++j) o[j] = (bf16)(((float)a[j] + (float)b2[j]) * rl);
    *(bf16x4*)&O[i] = o;
}

// ---------------- launch ----------------
extern "C" void kernel_launch(void* const* d_in, const int* in_sizes, int n_in,
                              void* d_out, int out_size, void* d_ws, size_t ws_size,
                              hipStream_t stream) {
    const float* x  = (const float*)d_in[0];
    const float* Wq = (const float*)d_in[1];
    const float* Wk = (const float*)d_in[2];
    const float* Wv = (const float*)d_in[3];
    const float* Wo = (const float*)d_in[4];
    const float* bo = (const float*)d_in[5];
    float* out = (float*)d_out;

    char* ws = (char*)d_ws;
    const size_t MB = 1024 * 1024;
    bf16* xb    = (bf16*)(ws + (size_t)0);
    bf16* wqb   = (bf16*)(ws + 8 * MB);
    bf16* wkb   = (bf16*)(ws + 10 * MB);
    bf16* wvb   = (bf16*)(ws + 12 * MB);
    bf16* wob   = (bf16*)(ws + 14 * MB);
    bf16* Qb    = (bf16*)(ws + 16 * MB);
    bf16* Kb    = (bf16*)(ws + 24 * MB);
    bf16* Vt    = (bf16*)(ws + 32 * MB);
    bf16* Ab    = (bf16*)(ws + 40 * MB);
    bf16* Opart = (bf16*)(ws + 48 * MB);   // 2 x 8 MB
    float* Lp   = (float*)(ws + 64 * MB);  // 0.5 MB
    const bool split2 = ws_size >= 68 * MB;

    f2b_kernel<<<4096, 256, 0, stream>>>(x, xb, 4096 * 1024);
    w2b_kernel<<<4096, 256, 0, stream>>>(Wq, Wk, Wv, Wo, wqb, wkb, wvb, wob);

    gemm_qkv_kernel<<<dim3(32, 8, 3), 256, 0, stream>>>(xb, wqb, wkb, wvb, Qb, Kb, Vt);
    if (split2) {
        attn_kernel<2><<<dim3(32, 16, 2), 256, 0, stream>>>(Qb, Kb, Vt, nullptr, Opart, Lp);
        attn_merge_kernel<<<4096, 256, 0, stream>>>(Opart, Lp, Ab);
    } else {
        attn_kernel<1><<<dim3(32, 16, 1), 256, 0, stream>>>(Qb, Kb, Vt, Ab, nullptr, nullptr);
    }
    gemm_out_kernel<<<dim3(32, 8), 256, 0, stream>>>(Ab, wob, out, bo);
}

// Round 6
// 164.009 us; speedup vs baseline: 2.0664x; 2.0664x over previous
//
#include <hip/hip_runtime.h>
#include <hip/hip_bf16.h>

// ParallelMHA: B=2, N=2048, D=1024, H=16, HD=64. fp32 in/out, bf16 MFMA compute.
// Pipeline: converts -> QKV GEMM (gload_lds staging; Q*log2e/8, V transposed)
//           -> flash attn (fixed-max softmax, K-split x2 + merge) -> O GEMM
// R5 post-mortem: launch_bounds(256,4) forced VGPR 120->64 => scratch spill, 1GB/dispatch.
// R6: revert to (256,2) (120 VGPR already permits 4 waves/SIMD), keep K-split.

typedef __bf16 bf16;
typedef __bf16 bf16x4 __attribute__((ext_vector_type(4)));
typedef __bf16 bf16x8 __attribute__((ext_vector_type(8)));
typedef float f32x4 __attribute__((ext_vector_type(4)));

__device__ __forceinline__ f32x4 mfma16(bf16x8 a, bf16x8 b, f32x4 c) {
    return __builtin_amdgcn_mfma_f32_16x16x32_bf16(a, b, c, 0, 0, 0);
}

__device__ __forceinline__ void gload16(const bf16* g, bf16* l) {
    __builtin_amdgcn_global_load_lds(
        (const __attribute__((address_space(1))) unsigned int*)g,
        (__attribute__((address_space(3))) unsigned int*)l, 16, 0, 0);
}

// ---------------- fp32 -> bf16 converts ----------------
__global__ __launch_bounds__(256) void f2b_kernel(const float* __restrict__ in,
                                                  bf16* __restrict__ out, int n) {
    int i = (blockIdx.x * 256 + threadIdx.x) * 4;
    if (i >= n) return;
    float4 v = *(const float4*)&in[i];
    bf16x4 o;
    o.x = (bf16)v.x; o.y = (bf16)v.y; o.z = (bf16)v.z; o.w = (bf16)v.w;
    *(bf16x4*)&out[i] = o;
}

// all four 1024x1024 weights in one launch: 4096 blocks, 1024 per matrix
__global__ __launch_bounds__(256) void w2b_kernel(
    const float* __restrict__ w0, const float* __restrict__ w1,
    const float* __restrict__ w2, const float* __restrict__ w3,
    bf16* __restrict__ o0, bf16* __restrict__ o1,
    bf16* __restrict__ o2, bf16* __restrict__ o3) {
    int sel = blockIdx.x >> 10;
    const float* in = sel == 0 ? w0 : sel == 1 ? w1 : sel == 2 ? w2 : w3;
    bf16* out = sel == 0 ? o0 : sel == 1 ? o1 : sel == 2 ? o2 : o3;
    int i = ((blockIdx.x & 1023) * 256 + threadIdx.x) * 4;
    float4 v = *(const float4*)&in[i];
    bf16x4 o;
    o.x = (bf16)v.x; o.y = (bf16)v.y; o.z = (bf16)v.z; o.w = (bf16)v.w;
    *(bf16x4*)&out[i] = o;
}

// ---------------- 128x128 bf16 GEMM, global_load_lds staging (m97 structure) -------
// C = A[M,K] @ B[N,K]^T. MODE 0: bf16 out *scale. MODE 1: f32 out + bias.
// MODE 2: bf16 out transposed (C[col][row], ld ldt).
template <int MODE>
__device__ __forceinline__ void gemm_body(const bf16* __restrict__ A,
                                          const bf16* __restrict__ B,
                                          bf16* __restrict__ Cb,
                                          float* __restrict__ Cf,
                                          const float* __restrict__ bias,
                                          float scale, int N, int K, int row0, int col0,
                                          int ldt) {
    __shared__ alignas(16) bf16 sA[128 * 32];
    __shared__ alignas(16) bf16 sB[128 * 32];
    const int tid  = threadIdx.x;
    const int lane = tid & 63;
    const int wave = tid >> 6;
    const int wrow = (wave >> 1) * 64;
    const int wcol = (wave & 1) * 64;
    const int la = lane & 15, lb = lane >> 4;

    const f32x4 fzero = {0.f, 0.f, 0.f, 0.f};
    f32x4 acc[4][4];
#pragma unroll
    for (int m = 0; m < 4; ++m)
#pragma unroll
        for (int n = 0; n < 4; ++n) acc[m][n] = fzero;

    for (int k0 = 0; k0 < K; k0 += 32) {
        // async global -> LDS staging, 16B/lane, layout linear in tid
#pragma unroll
        for (int i = 0; i < 2; ++i) {
            int idx = i * 256 + tid;
            int r = idx >> 2, s = idx & 3;
            gload16(&A[(size_t)(row0 + r) * K + k0 + s * 8], &sA[idx * 8]);
            gload16(&B[(size_t)(col0 + r) * K + k0 + s * 8], &sB[idx * 8]);
        }
        __syncthreads();
        bf16x8 af[4], bfv[4];
#pragma unroll
        for (int m = 0; m < 4; ++m)
            af[m] = *(const bf16x8*)&sA[(wrow + m * 16 + la) * 32 + lb * 8];
#pragma unroll
        for (int n = 0; n < 4; ++n)
            bfv[n] = *(const bf16x8*)&sB[(wcol + n * 16 + la) * 32 + lb * 8];
#pragma unroll
        for (int m = 0; m < 4; ++m)
#pragma unroll
            for (int n = 0; n < 4; ++n)
                acc[m][n] = mfma16(af[m], bfv[n], acc[m][n]);
        __syncthreads();
    }
#pragma unroll
    for (int m = 0; m < 4; ++m)
#pragma unroll
        for (int n = 0; n < 4; ++n) {
            int col = col0 + wcol + n * 16 + la;
            if (MODE == 2) {
                bf16x4 o4;
#pragma unroll
                for (int r = 0; r < 4; ++r) o4[r] = (bf16)acc[m][n][r];
                *(bf16x4*)&Cb[(size_t)col * ldt + row0 + wrow + m * 16 + lb * 4] = o4;
            } else {
#pragma unroll
                for (int r = 0; r < 4; ++r) {
                    int row = row0 + wrow + m * 16 + lb * 4 + r;
                    if (MODE == 1)
                        Cf[(size_t)row * N + col] = acc[m][n][r] + bias[col];
                    else
                        Cb[(size_t)row * N + col] = (bf16)(acc[m][n][r] * scale);
                }
            }
        }
}

__global__ __launch_bounds__(256) void gemm_qkv_kernel(
    const bf16* __restrict__ xb, const bf16* __restrict__ wq,
    const bf16* __restrict__ wk, const bf16* __restrict__ wv,
    bf16* __restrict__ Q, bf16* __restrict__ Kb, bf16* __restrict__ Vt) {
    int z = blockIdx.z;
    if (z == 2) {
        gemm_body<2>(xb, wv, Vt, nullptr, nullptr, 1.f, 1024, 1024,
                     blockIdx.x * 128, blockIdx.y * 128, 4096);
    } else {
        // Q scale = log2(e)/8 (exp2-based softmax); K scale = 1
        gemm_body<0>(xb, z ? wk : wq, z ? Kb : Q, nullptr, nullptr,
                     z ? 1.0f : 0.1803368801111204f, 1024, 1024,
                     blockIdx.x * 128, blockIdx.y * 128, 0);
    }
}

__global__ __launch_bounds__(256) void gemm_out_kernel(
    const bf16* __restrict__ att, const bf16* __restrict__ wo,
    float* __restrict__ out, const float* __restrict__ bias) {
    gemm_body<1>(att, wo, nullptr, out, bias, 1.f, 1024, 1024,
                 blockIdx.x * 128, blockIdx.y * 128, 0);
}

// ---------------- flash attention (causal), fixed-max softmax, K-split ----------------
// Q/K/O: [b*2048+n][h*64+hd] (ld 1024); Vt: [h*64+hd][b*2048+n] (ld 4096).
// 4 independent waves/block, 32 q-rows/wave, KBLK=64. p = exp2(s - 10*log2e).
// SPLITS==2: blockIdx.z halves each wave's tile range; partials additive (fixed max).
struct KF { bf16x8 f[4][2]; };

template <int SPLITS>
__global__ __launch_bounds__(256, 2) void attn_kernel(
    const bf16* __restrict__ Q, const bf16* __restrict__ K,
    const bf16* __restrict__ Vt, bf16* __restrict__ O,
    bf16* __restrict__ Opart, float* __restrict__ Lpart) {
    __shared__ alignas(16) char Plds[4][4096];  // per-wave P[32][64] bf16, XOR-swizzled
    const int lane = threadIdx.x & 63;
    const int wave = threadIdx.x >> 6;
    const int slot = blockIdx.y;
    const int qt = slot < 8 ? slot : 23 - slot;  // long+short pairing
    const int h = blockIdx.x & 15;
    const int b = blockIdx.x >> 4;
    const int split = (SPLITS == 2) ? blockIdx.z : 0;
    const int q0w = qt * 128 + wave * 32;
    const int rowbase = b * 2048;
    const int colbase = h * 64;
    const int la = lane & 15, lb = lane >> 4;
    const f32x4 fzero = {0.f, 0.f, 0.f, 0.f};
    char* pbase = Plds[wave];
    const float C = 14.426950408889634f;  // 10 * log2(e)

    bf16x8 aq[2][2];
#pragma unroll
    for (int mf = 0; mf < 2; ++mf) {
        const bf16* qp = &Q[(size_t)(rowbase + q0w + mf * 16 + la) * 1024 + colbase];
#pragma unroll
        for (int kc = 0; kc < 2; ++kc) aq[mf][kc] = *(const bf16x8*)(qp + kc * 32 + lb * 8);
    }

    bf16x8 bones;
#pragma unroll
    for (int j = 0; j < 8; ++j) bones[j] = (bf16)1.0f;

    f32x4 o[2][4], lacc[2];
#pragma unroll
    for (int mf = 0; mf < 2; ++mf) {
        lacc[mf] = fzero;
#pragma unroll
        for (int hc = 0; hc < 4; ++hc) o[mf][hc] = fzero;
    }

    const int nt = (q0w + 95) >> 6;  // causal trip count for this wave
    int t0 = 0, t1 = nt;
    if (SPLITS == 2) {
        int half = nt >> 1;
        t0 = split ? half : 0;
        t1 = split ? nt : half;
    }

    KF ka, kb;
    if (t0 < t1) {
#pragma unroll
        for (int ck = 0; ck < 4; ++ck) {
            const bf16* kp = &K[(size_t)(rowbase + t0 * 64 + ck * 16 + la) * 1024 + colbase];
            ka.f[ck][0] = *(const bf16x8*)(kp + lb * 8);
            ka.f[ck][1] = *(const bf16x8*)(kp + 32 + lb * 8);
        }
    }

    auto TILE = [&](int tile, KF& kc, KF& kn, int pref) {
        const int k0 = tile * 64;
        const bool domask = (tile == nt - 1);
        // V loads for this tile
        bf16x8 bv[4][2];
#pragma unroll
        for (int hc = 0; hc < 4; ++hc) {
            const bf16* vp = &Vt[(size_t)(colbase + hc * 16 + la) * 4096 + rowbase + k0];
            bv[hc][0] = *(const bf16x8*)(vp + lb * 8);
            bv[hc][1] = *(const bf16x8*)(vp + 32 + lb * 8);
        }
        // K prefetch for next tile
#pragma unroll
        for (int ck = 0; ck < 4; ++ck) {
            const bf16* kp = &K[(size_t)(rowbase + pref * 64 + ck * 16 + la) * 1024 + colbase];
            kn.f[ck][0] = *(const bf16x8*)(kp + lb * 8);
            kn.f[ck][1] = *(const bf16x8*)(kp + 32 + lb * 8);
        }
        // S = Q @ K^T
        f32x4 s[2][4];
#pragma unroll
        for (int mf = 0; mf < 2; ++mf)
#pragma unroll
            for (int ck = 0; ck < 4; ++ck) s[mf][ck] = fzero;
        __builtin_amdgcn_s_setprio(1);
#pragma unroll
        for (int ck = 0; ck < 4; ++ck)
#pragma unroll
            for (int mf = 0; mf < 2; ++mf) {
                s[mf][ck] = mfma16(aq[mf][0], kc.f[ck][0], s[mf][ck]);
                s[mf][ck] = mfma16(aq[mf][1], kc.f[ck][1], s[mf][ck]);
            }
        __builtin_amdgcn_s_setprio(0);
        if (domask) {
#pragma unroll
            for (int mf = 0; mf < 2; ++mf)
#pragma unroll
                for (int ck = 0; ck < 4; ++ck) {
                    int key = k0 + ck * 16 + la;
#pragma unroll
                    for (int r = 0; r < 4; ++r) {
                        int qrow = q0w + mf * 16 + lb * 4 + r;
                        if (key > qrow) s[mf][ck][r] = -1e30f;
                    }
                }
        }
        // P = exp2(s - C) -> swizzled LDS (transpose to A-operand layout)
#pragma unroll
        for (int mf = 0; mf < 2; ++mf)
#pragma unroll
            for (int ck = 0; ck < 4; ++ck)
#pragma unroll
                for (int r = 0; r < 4; ++r) {
                    float p = __builtin_amdgcn_exp2f(s[mf][ck][r] - C);
                    int row = mf * 16 + lb * 4 + r;
                    int cb = (ck * 16 + la) * 2;
                    *(bf16*)(pbase + row * 128 + (cb ^ ((row & 7) << 4))) = (bf16)p;
                }
        __builtin_amdgcn_wave_barrier();
        bf16x8 pa[2][2];
#pragma unroll
        for (int mf = 0; mf < 2; ++mf)
#pragma unroll
            for (int kc2 = 0; kc2 < 2; ++kc2) {
                int row = mf * 16 + la;
                int cb = kc2 * 64 + lb * 16;
                pa[mf][kc2] =
                    *(const bf16x8*)(pbase + row * 128 + (cb ^ ((row & 7) << 4)));
            }
        // PV + l-sum via ones
        __builtin_amdgcn_s_setprio(1);
#pragma unroll
        for (int hc = 0; hc < 4; ++hc)
#pragma unroll
            for (int mf = 0; mf < 2; ++mf) {
                o[mf][hc] = mfma16(pa[mf][0], bv[hc][0], o[mf][hc]);
                o[mf][hc] = mfma16(pa[mf][1], bv[hc][1], o[mf][hc]);
            }
#pragma unroll
        for (int mf = 0; mf < 2; ++mf) {
            lacc[mf] = mfma16(pa[mf][0], bones, lacc[mf]);
            lacc[mf] = mfma16(pa[mf][1], bones, lacc[mf]);
        }
        __builtin_amdgcn_s_setprio(0);
        __builtin_amdgcn_wave_barrier();
    };

    int t = t0;
    for (; t + 2 <= t1; t += 2) {
        TILE(t, ka, kb, t + 1);
        TILE(t + 1, kb, ka, (t + 2 < t1 ? t + 2 : t1 - 1));
    }
    if (t < t1) TILE(t, ka, kb, t1 - 1);

    // epilogue
    if (SPLITS == 2) {
        bf16* op = Opart + (size_t)split * 4096 * 1024;
#pragma unroll
        for (int mf = 0; mf < 2; ++mf)
#pragma unroll
            for (int hc = 0; hc < 4; ++hc)
#pragma unroll
                for (int r = 0; r < 4; ++r) {
                    int qrow = q0w + mf * 16 + lb * 4 + r;
                    op[(size_t)(rowbase + qrow) * 1024 + colbase + hc * 16 + la] =
                        (bf16)o[mf][hc][r];
                }
        if (la == 0) {
#pragma unroll
            for (int mf = 0; mf < 2; ++mf)
#pragma unroll
                for (int r = 0; r < 4; ++r) {
                    int qrow = q0w + mf * 16 + lb * 4 + r;
                    Lpart[(size_t)split * 4096 * 16 + (size_t)(rowbase + qrow) * 16 + h] =
                        lacc[mf][r];
                }
        }
    } else {
#pragma unroll
        for (int mf = 0; mf < 2; ++mf)
#pragma unroll
            for (int hc = 0; hc < 4; ++hc)
#pragma unroll
                for (int r = 0; r < 4; ++r) {
                    int qrow = q0w + mf * 16 + lb * 4 + r;
                    O[(size_t)(rowbase + qrow) * 1024 + colbase + hc * 16 + la] =
                        (bf16)(o[mf][hc][r] / lacc[mf][r]);
                }
    }
}

__global__ __launch_bounds__(256) void attn_merge_kernel(
    const bf16* __restrict__ Opart, const float* __restrict__ Lpart,
    bf16* __restrict__ O) {
    int i = (blockIdx.x * 256 + threadIdx.x) * 4;
    int row = i >> 10, c = i & 1023, h = c >> 6;
    float l0 = Lpart[row * 16 + h];
    float l1 = Lpart[4096 * 16 + row * 16 + h];
    float rl = 1.f / (l0 + l1);
    bf16x4 a = *(const bf16x4*)&Opart[i];
    bf16x4 b2 = *(const bf16x4*)&Opart[(size_t)4096 * 1024 + i];
    bf16x4 o;
#pragma unroll
    for (int j = 0; j < 4; ++j) o[j] = (bf16)(((float)a[j] + (float)b2[j]) * rl);
    *(bf16x4*)&O[i] = o;
}

// ---------------- launch ----------------
extern "C" void kernel_launch(void* const* d_in, const int* in_sizes, int n_in,
                              void* d_out, int out_size, void* d_ws, size_t ws_size,
                              hipStream_t stream) {
    const float* x  = (const float*)d_in[0];
    const float* Wq = (const float*)d_in[1];
    const float* Wk = (const float*)d_in[2];
    const float* Wv = (const float*)d_in[3];
    const float* Wo = (const float*)d_in[4];
    const float* bo = (const float*)d_in[5];
    float* out = (float*)d_out;

    char* ws = (char*)d_ws;
    const size_t MB = 1024 * 1024;
    bf16* xb    = (bf16*)(ws + (size_t)0);
    bf16* wqb   = (bf16*)(ws + 8 * MB);
    bf16* wkb   = (bf16*)(ws + 10 * MB);
    bf16* wvb   = (bf16*)(ws + 12 * MB);
    bf16* wob   = (bf16*)(ws + 14 * MB);
    bf16* Qb    = (bf16*)(ws + 16 * MB);
    bf16* Kb    = (bf16*)(ws + 24 * MB);
    bf16* Vt    = (bf16*)(ws + 32 * MB);
    bf16* Ab    = (bf16*)(ws + 40 * MB);
    bf16* Opart = (bf16*)(ws + 48 * MB);   // 2 x 8 MB
    float* Lp   = (float*)(ws + 64 * MB);  // 0.5 MB
    const bool split2 = ws_size >= 68 * MB;

    f2b_kernel<<<4096, 256, 0, stream>>>(x, xb, 4096 * 1024);
    w2b_kernel<<<4096, 256, 0, stream>>>(Wq, Wk, Wv, Wo, wqb, wkb, wvb, wob);

    gemm_qkv_kernel<<<dim3(32, 8, 3), 256, 0, stream>>>(xb, wqb, wkb, wvb, Qb, Kb, Vt);
    if (split2) {
        attn_kernel<2><<<dim3(32, 16, 2), 256, 0, stream>>>(Qb, Kb, Vt, nullptr, Opart, Lp);
        attn_merge_kernel<<<4096, 256, 0, stream>>>(Opart, Lp, Ab);
    } else {
        attn_kernel<1><<<dim3(32, 16, 1), 256, 0, stream>>>(Qb, Kb, Vt, Ab, nullptr, nullptr);
    }
    gemm_out_kernel<<<dim3(32, 8), 256, 0, stream>>>(Ab, wob, out, bo);
}

// Round 7
// 132.158 us; speedup vs baseline: 2.5645x; 1.2410x over previous
//
#include <hip/hip_runtime.h>
#include <hip/hip_bf16.h>

// ParallelMHA: B=2, N=2048, D=1024, H=16, HD=64. fp32 in/out, bf16 MFMA compute.
// Pipeline: converts -> QKV GEMM (gload_lds staging; Q*log2e/8, V transposed)
//           -> flash attn (fixed-max softmax, XCD-pinned (b,h)) -> O GEMM
// R6 post-mortem: K-split added overhead, no occupancy gain. Root cause of attn
// latency: all 32 (b,h) interleaved on every XCD -> 16MB vs 4MB per-XCD L2 ->
// K/V re-reads served by L3 (~500cy). R7: swizzle bid so each XCD owns 4 (b,h)
// (2MB working set, L2-resident); revert split + setprio.

typedef __bf16 bf16;
typedef __bf16 bf16x4 __attribute__((ext_vector_type(4)));
typedef __bf16 bf16x8 __attribute__((ext_vector_type(8)));
typedef float f32x4 __attribute__((ext_vector_type(4)));

__device__ __forceinline__ f32x4 mfma16(bf16x8 a, bf16x8 b, f32x4 c) {
    return __builtin_amdgcn_mfma_f32_16x16x32_bf16(a, b, c, 0, 0, 0);
}

__device__ __forceinline__ void gload16(const bf16* g, bf16* l) {
    __builtin_amdgcn_global_load_lds(
        (const __attribute__((address_space(1))) unsigned int*)g,
        (__attribute__((address_space(3))) unsigned int*)l, 16, 0, 0);
}

// ---------------- fp32 -> bf16 converts ----------------
__global__ __launch_bounds__(256) void f2b_kernel(const float* __restrict__ in,
                                                  bf16* __restrict__ out, int n) {
    int i = (blockIdx.x * 256 + threadIdx.x) * 4;
    if (i >= n) return;
    float4 v = *(const float4*)&in[i];
    bf16x4 o;
    o.x = (bf16)v.x; o.y = (bf16)v.y; o.z = (bf16)v.z; o.w = (bf16)v.w;
    *(bf16x4*)&out[i] = o;
}

// all four 1024x1024 weights in one launch
__global__ __launch_bounds__(256) void w2b_kernel(
    const float* __restrict__ w0, const float* __restrict__ w1,
    const float* __restrict__ w2, const float* __restrict__ w3,
    bf16* __restrict__ o0, bf16* __restrict__ o1,
    bf16* __restrict__ o2, bf16* __restrict__ o3) {
    int sel = blockIdx.x >> 10;
    const float* in = sel == 0 ? w0 : sel == 1 ? w1 : sel == 2 ? w2 : w3;
    bf16* out = sel == 0 ? o0 : sel == 1 ? o1 : sel == 2 ? o2 : o3;
    int i = ((blockIdx.x & 1023) * 256 + threadIdx.x) * 4;
    float4 v = *(const float4*)&in[i];
    bf16x4 o;
    o.x = (bf16)v.x; o.y = (bf16)v.y; o.z = (bf16)v.z; o.w = (bf16)v.w;
    *(bf16x4*)&out[i] = o;
}

// ---------------- 128x128 bf16 GEMM, global_load_lds staging -------
// C = A[M,K] @ B[N,K]^T. MODE 0: bf16 out *scale. MODE 1: f32 out + bias.
// MODE 2: bf16 out transposed (C[col][row], ld ldt).
template <int MODE>
__device__ __forceinline__ void gemm_body(const bf16* __restrict__ A,
                                          const bf16* __restrict__ B,
                                          bf16* __restrict__ Cb,
                                          float* __restrict__ Cf,
                                          const float* __restrict__ bias,
                                          float scale, int N, int K, int row0, int col0,
                                          int ldt) {
    __shared__ alignas(16) bf16 sA[128 * 32];
    __shared__ alignas(16) bf16 sB[128 * 32];
    const int tid  = threadIdx.x;
    const int lane = tid & 63;
    const int wave = tid >> 6;
    const int wrow = (wave >> 1) * 64;
    const int wcol = (wave & 1) * 64;
    const int la = lane & 15, lb = lane >> 4;

    const f32x4 fzero = {0.f, 0.f, 0.f, 0.f};
    f32x4 acc[4][4];
#pragma unroll
    for (int m = 0; m < 4; ++m)
#pragma unroll
        for (int n = 0; n < 4; ++n) acc[m][n] = fzero;

    for (int k0 = 0; k0 < K; k0 += 32) {
#pragma unroll
        for (int i = 0; i < 2; ++i) {
            int idx = i * 256 + tid;
            int r = idx >> 2, s = idx & 3;
            gload16(&A[(size_t)(row0 + r) * K + k0 + s * 8], &sA[idx * 8]);
            gload16(&B[(size_t)(col0 + r) * K + k0 + s * 8], &sB[idx * 8]);
        }
        __syncthreads();
        bf16x8 af[4], bfv[4];
#pragma unroll
        for (int m = 0; m < 4; ++m)
            af[m] = *(const bf16x8*)&sA[(wrow + m * 16 + la) * 32 + lb * 8];
#pragma unroll
        for (int n = 0; n < 4; ++n)
            bfv[n] = *(const bf16x8*)&sB[(wcol + n * 16 + la) * 32 + lb * 8];
#pragma unroll
        for (int m = 0; m < 4; ++m)
#pragma unroll
            for (int n = 0; n < 4; ++n)
                acc[m][n] = mfma16(af[m], bfv[n], acc[m][n]);
        __syncthreads();
    }
#pragma unroll
    for (int m = 0; m < 4; ++m)
#pragma unroll
        for (int n = 0; n < 4; ++n) {
            int col = col0 + wcol + n * 16 + la;
            if (MODE == 2) {
                bf16x4 o4;
#pragma unroll
                for (int r = 0; r < 4; ++r) o4[r] = (bf16)acc[m][n][r];
                *(bf16x4*)&Cb[(size_t)col * ldt + row0 + wrow + m * 16 + lb * 4] = o4;
            } else {
#pragma unroll
                for (int r = 0; r < 4; ++r) {
                    int row = row0 + wrow + m * 16 + lb * 4 + r;
                    if (MODE == 1)
                        Cf[(size_t)row * N + col] = acc[m][n][r] + bias[col];
                    else
                        Cb[(size_t)row * N + col] = (bf16)(acc[m][n][r] * scale);
                }
            }
        }
}

__global__ __launch_bounds__(256) void gemm_qkv_kernel(
    const bf16* __restrict__ xb, const bf16* __restrict__ wq,
    const bf16* __restrict__ wk, const bf16* __restrict__ wv,
    bf16* __restrict__ Q, bf16* __restrict__ Kb, bf16* __restrict__ Vt) {
    int z = blockIdx.z;
    if (z == 2) {
        gemm_body<2>(xb, wv, Vt, nullptr, nullptr, 1.f, 1024, 1024,
                     blockIdx.x * 128, blockIdx.y * 128, 4096);
    } else {
        // Q scale = log2(e)/8 (exp2-based softmax); K scale = 1
        gemm_body<0>(xb, z ? wk : wq, z ? Kb : Q, nullptr, nullptr,
                     z ? 1.0f : 0.1803368801111204f, 1024, 1024,
                     blockIdx.x * 128, blockIdx.y * 128, 0);
    }
}

__global__ __launch_bounds__(256) void gemm_out_kernel(
    const bf16* __restrict__ att, const bf16* __restrict__ wo,
    float* __restrict__ out, const float* __restrict__ bias) {
    gemm_body<1>(att, wo, nullptr, out, bias, 1.f, 1024, 1024,
                 blockIdx.x * 128, blockIdx.y * 128, 0);
}

// ---------------- flash attention (causal), fixed-max softmax, XCD-pinned ----------------
// Q/K/O: [b*2048+n][h*64+hd] (ld 1024); Vt: [h*64+hd][b*2048+n] (ld 4096).
// 4 independent waves/block, 32 q-rows/wave, KBLK=64. p = exp2(s - 10*log2e).
// 1-D grid of 512; bid&7 = XCD (round-robin heuristic): each XCD owns 4 (b,h)
// pairs -> 2MB K/V working set, fits 4MB per-XCD L2.
struct KF { bf16x8 f[4][2]; };

__global__ __launch_bounds__(256, 2) void attn_kernel(
    const bf16* __restrict__ Q, const bf16* __restrict__ K,
    const bf16* __restrict__ Vt, bf16* __restrict__ O) {
    __shared__ alignas(16) char Plds[4][4096];  // per-wave P[32][64] bf16, XOR-swizzled
    const int lane = threadIdx.x & 63;
    const int wave = threadIdx.x >> 6;
    const int bid = blockIdx.x;          // 0..511
    const int bh = (bid & 7) * 4 + ((bid >> 3) & 3);  // XCD-pinned (b,h)
    const int slot = bid >> 5;           // 0..15
    const int qt = slot < 8 ? slot : 23 - slot;  // long+short pairing
    const int h = bh & 15;
    const int b = bh >> 4;
    const int q0w = qt * 128 + wave * 32;
    const int rowbase = b * 2048;
    const int colbase = h * 64;
    const int la = lane & 15, lb = lane >> 4;
    const f32x4 fzero = {0.f, 0.f, 0.f, 0.f};
    char* pbase = Plds[wave];
    const float C = 14.426950408889634f;  // 10 * log2(e)

    bf16x8 aq[2][2];
#pragma unroll
    for (int mf = 0; mf < 2; ++mf) {
        const bf16* qp = &Q[(size_t)(rowbase + q0w + mf * 16 + la) * 1024 + colbase];
#pragma unroll
        for (int kc = 0; kc < 2; ++kc) aq[mf][kc] = *(const bf16x8*)(qp + kc * 32 + lb * 8);
    }

    bf16x8 bones;
#pragma unroll
    for (int j = 0; j < 8; ++j) bones[j] = (bf16)1.0f;

    f32x4 o[2][4], lacc[2];
#pragma unroll
    for (int mf = 0; mf < 2; ++mf) {
        lacc[mf] = fzero;
#pragma unroll
        for (int hc = 0; hc < 4; ++hc) o[mf][hc] = fzero;
    }

    const int nt = (q0w + 95) >> 6;  // exact causal trip count

    KF ka, kb;
#pragma unroll
    for (int ck = 0; ck < 4; ++ck) {  // initial K tile -> ka
        const bf16* kp = &K[(size_t)(rowbase + ck * 16 + la) * 1024 + colbase];
        ka.f[ck][0] = *(const bf16x8*)(kp + lb * 8);
        ka.f[ck][1] = *(const bf16x8*)(kp + 32 + lb * 8);
    }

    auto TILE = [&](int tile, KF& kc, KF& kn, int pref) {
        const int k0 = tile * 64;
        const bool domask = (tile == nt - 1);
        // V loads for this tile (consumed at PV, end of tile)
        bf16x8 bv[4][2];
#pragma unroll
        for (int hc = 0; hc < 4; ++hc) {
            const bf16* vp = &Vt[(size_t)(colbase + hc * 16 + la) * 4096 + rowbase + k0];
            bv[hc][0] = *(const bf16x8*)(vp + lb * 8);
            bv[hc][1] = *(const bf16x8*)(vp + 32 + lb * 8);
        }
        // K prefetch for next tile
#pragma unroll
        for (int ck = 0; ck < 4; ++ck) {
            const bf16* kp = &K[(size_t)(rowbase + pref * 64 + ck * 16 + la) * 1024 + colbase];
            kn.f[ck][0] = *(const bf16x8*)(kp + lb * 8);
            kn.f[ck][1] = *(const bf16x8*)(kp + 32 + lb * 8);
        }
        // S = Q @ K^T
        f32x4 s[2][4];
#pragma unroll
        for (int mf = 0; mf < 2; ++mf)
#pragma unroll
            for (int ck = 0; ck < 4; ++ck) s[mf][ck] = fzero;
#pragma unroll
        for (int ck = 0; ck < 4; ++ck)
#pragma unroll
            for (int mf = 0; mf < 2; ++mf) {
                s[mf][ck] = mfma16(aq[mf][0], kc.f[ck][0], s[mf][ck]);
                s[mf][ck] = mfma16(aq[mf][1], kc.f[ck][1], s[mf][ck]);
            }
        if (domask) {
#pragma unroll
            for (int mf = 0; mf < 2; ++mf)
#pragma unroll
                for (int ck = 0; ck < 4; ++ck) {
                    int key = k0 + ck * 16 + la;
#pragma unroll
                    for (int r = 0; r < 4; ++r) {
                        int qrow = q0w + mf * 16 + lb * 4 + r;
                        if (key > qrow) s[mf][ck][r] = -1e30f;
                    }
                }
        }
        // P = exp2(s - C) -> swizzled LDS (transpose to A-operand layout)
#pragma unroll
        for (int mf = 0; mf < 2; ++mf)
#pragma unroll
            for (int ck = 0; ck < 4; ++ck)
#pragma unroll
                for (int r = 0; r < 4; ++r) {
                    float p = __builtin_amdgcn_exp2f(s[mf][ck][r] - C);
                    int row = mf * 16 + lb * 4 + r;
                    int cb = (ck * 16 + la) * 2;
                    *(bf16*)(pbase + row * 128 + (cb ^ ((row & 7) << 4))) = (bf16)p;
                }
        __builtin_amdgcn_wave_barrier();
        bf16x8 pa[2][2];
#pragma unroll
        for (int mf = 0; mf < 2; ++mf)
#pragma unroll
            for (int kc2 = 0; kc2 < 2; ++kc2) {
                int row = mf * 16 + la;
                int cb = kc2 * 64 + lb * 16;
                pa[mf][kc2] =
                    *(const bf16x8*)(pbase + row * 128 + (cb ^ ((row & 7) << 4)));
            }
        // PV + l-sum via ones
#pragma unroll
        for (int hc = 0; hc < 4; ++hc)
#pragma unroll
            for (int mf = 0; mf < 2; ++mf) {
                o[mf][hc] = mfma16(pa[mf][0], bv[hc][0], o[mf][hc]);
                o[mf][hc] = mfma16(pa[mf][1], bv[hc][1], o[mf][hc]);
            }
#pragma unroll
        for (int mf = 0; mf < 2; ++mf) {
            lacc[mf] = mfma16(pa[mf][0], bones, lacc[mf]);
            lacc[mf] = mfma16(pa[mf][1], bones, lacc[mf]);
        }
        __builtin_amdgcn_wave_barrier();
    };

    int t = 0;
    for (; t + 2 <= nt; t += 2) {
        TILE(t, ka, kb, t + 1);
        TILE(t + 1, kb, ka, (t + 2 < nt ? t + 2 : nt - 1));
    }
    if (t < nt) TILE(t, ka, kb, nt - 1);

    // epilogue
#pragma unroll
    for (int mf = 0; mf < 2; ++mf)
#pragma unroll
        for (int hc = 0; hc < 4; ++hc)
#pragma unroll
            for (int r = 0; r < 4; ++r) {
                int qrow = q0w + mf * 16 + lb * 4 + r;
                O[(size_t)(rowbase + qrow) * 1024 + colbase + hc * 16 + la] =
                    (bf16)(o[mf][hc][r] / lacc[mf][r]);
            }
}

// ---------------- launch ----------------
extern "C" void kernel_launch(void* const* d_in, const int* in_sizes, int n_in,
                              void* d_out, int out_size, void* d_ws, size_t ws_size,
                              hipStream_t stream) {
    const float* x  = (const float*)d_in[0];
    const float* Wq = (const float*)d_in[1];
    const float* Wk = (const float*)d_in[2];
    const float* Wv = (const float*)d_in[3];
    const float* Wo = (const float*)d_in[4];
    const float* bo = (const float*)d_in[5];
    float* out = (float*)d_out;

    char* ws = (char*)d_ws;
    const size_t MB = 1024 * 1024;
    bf16* xb  = (bf16*)(ws + (size_t)0);
    bf16* wqb = (bf16*)(ws + 8 * MB);
    bf16* wkb = (bf16*)(ws + 10 * MB);
    bf16* wvb = (bf16*)(ws + 12 * MB);
    bf16* wob = (bf16*)(ws + 14 * MB);
    bf16* Qb  = (bf16*)(ws + 16 * MB);
    bf16* Kb  = (bf16*)(ws + 24 * MB);
    bf16* Vt  = (bf16*)(ws + 32 * MB);
    bf16* Ab  = (bf16*)(ws + 40 * MB);

    f2b_kernel<<<4096, 256, 0, stream>>>(x, xb, 4096 * 1024);
    w2b_kernel<<<4096, 256, 0, stream>>>(Wq, Wk, Wv, Wo, wqb, wkb, wvb, wob);

    gemm_qkv_kernel<<<dim3(32, 8, 3), 256, 0, stream>>>(xb, wqb, wkb, wvb, Qb, Kb, Vt);
    attn_kernel<<<512, 256, 0, stream>>>(Qb, Kb, Vt, Ab);
    gemm_out_kernel<<<dim3(32, 8), 256, 0, stream>>>(Ab, wob, out, bo);
}

// Round 9
// 131.161 us; speedup vs baseline: 2.5840x; 1.0076x over previous
//
#include <hip/hip_runtime.h>
#include <hip/hip_bf16.h>

// ParallelMHA: B=2, N=2048, D=1024, H=16, HD=64. fp32 in/out, bf16 MFMA compute.
// Pipeline: converts -> QKV GEMM (gload_lds staging; Q*log2e/8, V transposed+key-permuted)
//           -> flash attn (fixed-max softmax, XCD-pinned, swapped-QK, zero-shuffle P) -> O GEMM
// R8 post-mortem: shfl re-layout read source-lane-evaluated pk[ck] (ck depends on lb)
// => lanes lb=1,2 got swapped frags. R9: NO cross-lane move at all — pa assembled from
// each lane's own pk words; V rows stored KEY-PERMUTED (within 64-blocks) so PV's
// B-operand pairs the matching keys: pos = blk64 + (c>>1)*32 + lb*8 + (c&1)*4 + r
// for key c*16+lb*4+r. Mask/ones-sum unaffected (pre-permutation / perm-invariant).

typedef __bf16 bf16;
typedef __bf16 bf16x4 __attribute__((ext_vector_type(4)));
typedef __bf16 bf16x8 __attribute__((ext_vector_type(8)));
typedef float f32x4 __attribute__((ext_vector_type(4)));
typedef unsigned int u32x4 __attribute__((ext_vector_type(4)));

__device__ __forceinline__ f32x4 mfma16(bf16x8 a, bf16x8 b, f32x4 c) {
    return __builtin_amdgcn_mfma_f32_16x16x32_bf16(a, b, c, 0, 0, 0);
}

__device__ __forceinline__ void gload16(const bf16* g, bf16* l) {
    __builtin_amdgcn_global_load_lds(
        (const __attribute__((address_space(1))) unsigned int*)g,
        (__attribute__((address_space(3))) unsigned int*)l, 16, 0, 0);
}

__device__ __forceinline__ unsigned pkbf16(float a, float b) {
    unsigned lo = (unsigned)__builtin_bit_cast(unsigned short, (bf16)a);
    unsigned hi = (unsigned)__builtin_bit_cast(unsigned short, (bf16)b);
    return lo | (hi << 16);
}

// ---------------- fp32 -> bf16 converts ----------------
__global__ __launch_bounds__(256) void f2b_kernel(const float* __restrict__ in,
                                                  bf16* __restrict__ out, int n) {
    int i = (blockIdx.x * 256 + threadIdx.x) * 4;
    if (i >= n) return;
    float4 v = *(const float4*)&in[i];
    bf16x4 o;
    o.x = (bf16)v.x; o.y = (bf16)v.y; o.z = (bf16)v.z; o.w = (bf16)v.w;
    *(bf16x4*)&out[i] = o;
}

__global__ __launch_bounds__(256) void w2b_kernel(
    const float* __restrict__ w0, const float* __restrict__ w1,
    const float* __restrict__ w2, const float* __restrict__ w3,
    bf16* __restrict__ o0, bf16* __restrict__ o1,
    bf16* __restrict__ o2, bf16* __restrict__ o3) {
    int sel = blockIdx.x >> 10;
    const float* in = sel == 0 ? w0 : sel == 1 ? w1 : sel == 2 ? w2 : w3;
    bf16* out = sel == 0 ? o0 : sel == 1 ? o1 : sel == 2 ? o2 : o3;
    int i = ((blockIdx.x & 1023) * 256 + threadIdx.x) * 4;
    float4 v = *(const float4*)&in[i];
    bf16x4 o;
    o.x = (bf16)v.x; o.y = (bf16)v.y; o.z = (bf16)v.z; o.w = (bf16)v.w;
    *(bf16x4*)&out[i] = o;
}

// ---------------- 128x128 bf16 GEMM, global_load_lds staging -------
// C = A[M,K] @ B[N,K]^T. MODE 0: bf16 out *scale. MODE 1: f32 out + bias.
// MODE 2: bf16 out transposed (C[col][row], ld ldt) with key-permuted rows
// (within 64-blocks) for attn's zero-shuffle PV pairing.
template <int MODE>
__device__ __forceinline__ void gemm_body(const bf16* __restrict__ A,
                                          const bf16* __restrict__ B,
                                          bf16* __restrict__ Cb,
                                          float* __restrict__ Cf,
                                          const float* __restrict__ bias,
                                          float scale, int N, int K, int row0, int col0,
                                          int ldt) {
    __shared__ alignas(16) bf16 sA[128 * 32];
    __shared__ alignas(16) bf16 sB[128 * 32];
    const int tid  = threadIdx.x;
    const int lane = tid & 63;
    const int wave = tid >> 6;
    const int wrow = (wave >> 1) * 64;
    const int wcol = (wave & 1) * 64;
    const int la = lane & 15, lb = lane >> 4;

    const f32x4 fzero = {0.f, 0.f, 0.f, 0.f};
    f32x4 acc[4][4];
#pragma unroll
    for (int m = 0; m < 4; ++m)
#pragma unroll
        for (int n = 0; n < 4; ++n) acc[m][n] = fzero;

    for (int k0 = 0; k0 < K; k0 += 32) {
#pragma unroll
        for (int i = 0; i < 2; ++i) {
            int idx = i * 256 + tid;
            int r = idx >> 2, s = idx & 3;
            gload16(&A[(size_t)(row0 + r) * K + k0 + s * 8], &sA[idx * 8]);
            gload16(&B[(size_t)(col0 + r) * K + k0 + s * 8], &sB[idx * 8]);
        }
        __syncthreads();
        bf16x8 af[4], bfv[4];
#pragma unroll
        for (int m = 0; m < 4; ++m)
            af[m] = *(const bf16x8*)&sA[(wrow + m * 16 + la) * 32 + lb * 8];
#pragma unroll
        for (int n = 0; n < 4; ++n)
            bfv[n] = *(const bf16x8*)&sB[(wcol + n * 16 + la) * 32 + lb * 8];
#pragma unroll
        for (int m = 0; m < 4; ++m)
#pragma unroll
            for (int n = 0; n < 4; ++n)
                acc[m][n] = mfma16(af[m], bfv[n], acc[m][n]);
        __syncthreads();
    }
#pragma unroll
    for (int m = 0; m < 4; ++m)
#pragma unroll
        for (int n = 0; n < 4; ++n) {
            int col = col0 + wcol + n * 16 + la;
            if (MODE == 2) {
                bf16x4 o4;
#pragma unroll
                for (int r = 0; r < 4; ++r) o4[r] = (bf16)acc[m][n][r];
                int sp = row0 + wrow + m * 16 + lb * 4;  // 4-aligned seq position
                int q64 = sp & 63, c = q64 >> 4;
                int p = (sp & ~63) | ((c >> 1) * 32 + ((q64 >> 2) & 3) * 8 + (c & 1) * 4);
                *(bf16x4*)&Cb[(size_t)col * ldt + p] = o4;
            } else {
#pragma unroll
                for (int r = 0; r < 4; ++r) {
                    int row = row0 + wrow + m * 16 + lb * 4 + r;
                    if (MODE == 1)
                        Cf[(size_t)row * N + col] = acc[m][n][r] + bias[col];
                    else
                        Cb[(size_t)row * N + col] = (bf16)(acc[m][n][r] * scale);
                }
            }
        }
}

__global__ __launch_bounds__(256) void gemm_qkv_kernel(
    const bf16* __restrict__ xb, const bf16* __restrict__ wq,
    const bf16* __restrict__ wk, const bf16* __restrict__ wv,
    bf16* __restrict__ Q, bf16* __restrict__ Kb, bf16* __restrict__ Vt) {
    int z = blockIdx.z;
    if (z == 2) {
        gemm_body<2>(xb, wv, Vt, nullptr, nullptr, 1.f, 1024, 1024,
                     blockIdx.x * 128, blockIdx.y * 128, 4096);
    } else {
        gemm_body<0>(xb, z ? wk : wq, z ? Kb : Q, nullptr, nullptr,
                     z ? 1.0f : 0.1803368801111204f, 1024, 1024,
                     blockIdx.x * 128, blockIdx.y * 128, 0);
    }
}

__global__ __launch_bounds__(256) void gemm_out_kernel(
    const bf16* __restrict__ att, const bf16* __restrict__ wo,
    float* __restrict__ out, const float* __restrict__ bias) {
    gemm_body<1>(att, wo, nullptr, out, bias, 1.f, 1024, 1024,
                 blockIdx.x * 128, blockIdx.y * 128, 0);
}

// ---------------- flash attention (causal), swapped-QK, zero-shuffle P ----------------
// Q/K/O: [b*2048+n][h*64+hd] (ld 1024); Vt: [h*64+hd][b*2048+n] (ld 4096, key-permuted).
// 4 waves/block, 32 q-rows/wave, KBLK=64. p = exp2(s - 10*log2e), fixed max.
// S^T = mfma(K, Q): lane (la,lb) holds keys ck*16+lb*4+r for q-row la.
// pa[mf][kc2] = own-lane pk words; V permutation provides the matching key order.
struct KF { bf16x8 f[4][2]; };

__global__ __launch_bounds__(256, 2) void attn_kernel(
    const bf16* __restrict__ Q, const bf16* __restrict__ K,
    const bf16* __restrict__ Vt, bf16* __restrict__ O) {
    const int lane = threadIdx.x & 63;
    const int wave = threadIdx.x >> 6;
    const int bid = blockIdx.x;                       // 0..511
    const int bh = (bid & 7) * 4 + ((bid >> 3) & 3);  // XCD-pinned (b,h)
    const int slot = bid >> 5;                        // 0..15
    const int qt = slot < 8 ? slot : 23 - slot;       // long+short pairing
    const int h = bh & 15;
    const int b = bh >> 4;
    const int q0w = qt * 128 + wave * 32;
    const int rowbase = b * 2048;
    const int colbase = h * 64;
    const int la = lane & 15, lb = lane >> 4;
    const f32x4 fzero = {0.f, 0.f, 0.f, 0.f};
    const float C = 14.426950408889634f;  // 10 * log2(e)

    bf16x8 aq[2][2];
#pragma unroll
    for (int mf = 0; mf < 2; ++mf) {
        const bf16* qp = &Q[(size_t)(rowbase + q0w + mf * 16 + la) * 1024 + colbase];
#pragma unroll
        for (int kc = 0; kc < 2; ++kc) aq[mf][kc] = *(const bf16x8*)(qp + kc * 32 + lb * 8);
    }

    bf16x8 bones;
#pragma unroll
    for (int j = 0; j < 8; ++j) bones[j] = (bf16)1.0f;

    f32x4 o[2][4], lacc[2];
#pragma unroll
    for (int mf = 0; mf < 2; ++mf) {
        lacc[mf] = fzero;
#pragma unroll
        for (int hc = 0; hc < 4; ++hc) o[mf][hc] = fzero;
    }

    const int nt = (q0w + 95) >> 6;  // exact causal trip count

    KF ka, kb;
#pragma unroll
    for (int ck = 0; ck < 4; ++ck) {  // initial K tile -> ka
        const bf16* kp = &K[(size_t)(rowbase + ck * 16 + la) * 1024 + colbase];
        ka.f[ck][0] = *(const bf16x8*)(kp + lb * 8);
        ka.f[ck][1] = *(const bf16x8*)(kp + 32 + lb * 8);
    }

    auto TILE = [&](int tile, KF& kc, KF& kn, int pref) {
        const int k0 = tile * 64;
        const bool domask = (tile == nt - 1);
        // V loads for this tile (key-permuted rows match pa's key order)
        bf16x8 bv[4][2];
#pragma unroll
        for (int hc = 0; hc < 4; ++hc) {
            const bf16* vp = &Vt[(size_t)(colbase + hc * 16 + la) * 4096 + rowbase + k0];
            bv[hc][0] = *(const bf16x8*)(vp + lb * 8);
            bv[hc][1] = *(const bf16x8*)(vp + 32 + lb * 8);
        }
        // K prefetch for next tile
#pragma unroll
        for (int ck = 0; ck < 4; ++ck) {
            const bf16* kp = &K[(size_t)(rowbase + pref * 64 + ck * 16 + la) * 1024 + colbase];
            kn.f[ck][0] = *(const bf16x8*)(kp + lb * 8);
            kn.f[ck][1] = *(const bf16x8*)(kp + 32 + lb * 8);
        }
        // S^T = K @ Q^T : lane holds keys (k0 + ck*16 + lb*4 + r) for q-row (q0w+mf*16+la)
        f32x4 s[2][4];
#pragma unroll
        for (int mf = 0; mf < 2; ++mf)
#pragma unroll
            for (int ck = 0; ck < 4; ++ck) s[mf][ck] = fzero;
#pragma unroll
        for (int ck = 0; ck < 4; ++ck)
#pragma unroll
            for (int mf = 0; mf < 2; ++mf) {
                s[mf][ck] = mfma16(kc.f[ck][0], aq[mf][0], s[mf][ck]);
                s[mf][ck] = mfma16(kc.f[ck][1], aq[mf][1], s[mf][ck]);
            }
        if (domask) {
#pragma unroll
            for (int mf = 0; mf < 2; ++mf) {
                int qrow = q0w + mf * 16 + la;
#pragma unroll
                for (int ck = 0; ck < 4; ++ck)
#pragma unroll
                    for (int r = 0; r < 4; ++r) {
                        int key = k0 + ck * 16 + lb * 4 + r;
                        if (key > qrow) s[mf][ck][r] = -1e30f;
                    }
            }
        }
        // P = exp2(s - C); pack pairs; assemble PV A-frags from OWN lane (no shuffles)
        bf16x8 pa[2][2];
#pragma unroll
        for (int mf = 0; mf < 2; ++mf) {
            unsigned pk[4][2];
#pragma unroll
            for (int ck = 0; ck < 4; ++ck) {
                float p0 = __builtin_amdgcn_exp2f(s[mf][ck][0] - C);
                float p1 = __builtin_amdgcn_exp2f(s[mf][ck][1] - C);
                float p2 = __builtin_amdgcn_exp2f(s[mf][ck][2] - C);
                float p3 = __builtin_amdgcn_exp2f(s[mf][ck][3] - C);
                pk[ck][0] = pkbf16(p0, p1);
                pk[ck][1] = pkbf16(p2, p3);
            }
#pragma unroll
            for (int kc2 = 0; kc2 < 2; ++kc2) {
                u32x4 w;
                w.x = pk[kc2 * 2][0];
                w.y = pk[kc2 * 2][1];
                w.z = pk[kc2 * 2 + 1][0];
                w.w = pk[kc2 * 2 + 1][1];
                pa[mf][kc2] = __builtin_bit_cast(bf16x8, w);
            }
        }
        // PV + l-sum via ones
#pragma unroll
        for (int hc = 0; hc < 4; ++hc)
#pragma unroll
            for (int mf = 0; mf < 2; ++mf) {
                o[mf][hc] = mfma16(pa[mf][0], bv[hc][0], o[mf][hc]);
                o[mf][hc] = mfma16(pa[mf][1], bv[hc][1], o[mf][hc]);
            }
#pragma unroll
        for (int mf = 0; mf < 2; ++mf) {
            lacc[mf] = mfma16(pa[mf][0], bones, lacc[mf]);
            lacc[mf] = mfma16(pa[mf][1], bones, lacc[mf]);
        }
    };

    int t = 0;
    for (; t + 2 <= nt; t += 2) {
        TILE(t, ka, kb, t + 1);
        TILE(t + 1, kb, ka, (t + 2 < nt ? t + 2 : nt - 1));
    }
    if (t < nt) TILE(t, ka, kb, nt - 1);

    // epilogue: o row = q-sub lb*4+r, col = hd = hc*16+la
#pragma unroll
    for (int mf = 0; mf < 2; ++mf)
#pragma unroll
        for (int hc = 0; hc < 4; ++hc)
#pragma unroll
            for (int r = 0; r < 4; ++r) {
                int qrow = q0w + mf * 16 + lb * 4 + r;
                O[(size_t)(rowbase + qrow) * 1024 + colbase + hc * 16 + la] =
                    (bf16)(o[mf][hc][r] / lacc[mf][r]);
            }
}

// ---------------- launch ----------------
extern "C" void kernel_launch(void* const* d_in, const int* in_sizes, int n_in,
                              void* d_out, int out_size, void* d_ws, size_t ws_size,
                              hipStream_t stream) {
    const float* x  = (const float*)d_in[0];
    const float* Wq = (const float*)d_in[1];
    const float* Wk = (const float*)d_in[2];
    const float* Wv = (const float*)d_in[3];
    const float* Wo = (const float*)d_in[4];
    const float* bo = (const float*)d_in[5];
    float* out = (float*)d_out;

    char* ws = (char*)d_ws;
    const size_t MB = 1024 * 1024;
    bf16* xb  = (bf16*)(ws + (size_t)0);
    bf16* wqb = (bf16*)(ws + 8 * MB);
    bf16* wkb = (bf16*)(ws + 10 * MB);
    bf16* wvb = (bf16*)(ws + 12 * MB);
    bf16* wob = (bf16*)(ws + 14 * MB);
    bf16* Qb  = (bf16*)(ws + 16 * MB);
    bf16* Kb  = (bf16*)(ws + 24 * MB);
    bf16* Vt  = (bf16*)(ws + 32 * MB);
    bf16* Ab  = (bf16*)(ws + 40 * MB);

    f2b_kernel<<<4096, 256, 0, stream>>>(x, xb, 4096 * 1024);
    w2b_kernel<<<4096, 256, 0, stream>>>(Wq, Wk, Wv, Wo, wqb, wkb, wvb, wob);

    gemm_qkv_kernel<<<dim3(32, 8, 3), 256, 0, stream>>>(xb, wqb, wkb, wvb, Qb, Kb, Vt);
    attn_kernel<<<512, 256, 0, stream>>>(Qb, Kb, Vt, Ab);
    gemm_out_kernel<<<dim3(32, 8), 256, 0, stream>>>(Ab, wob, out, bo);
}

// Round 10
// 102.461 us; speedup vs baseline: 3.3077x; 1.2801x over previous
//
#include <hip/hip_runtime.h>
#include <hip/hip_bf16.h>

// ParallelMHA: B=2, N=2048, D=1024, H=16, HD=64. fp32 in/out, bf16 MFMA compute.
// Pipeline: converts -> QKV GEMM (gload_lds staging; Q*log2e/8; K,V stored in
//           FRAGMENT-DIRECT tiled layout) -> flash attn (fixed-max softmax,
//           XCD-pinned, swapped-QK, zero-shuffle P, dense 1KB loads) -> O GEMM
// R9 post-mortem: removing P-LDS was neutral (68.6us) => limiter is the K/V load
// stream: row-strided fragment loads = 16 x 64B segments / instr (1/4-dense).
// R10: K/V stored per (ktile,h) as 8KB contiguous blocks in per-lane fragment
// order => every attn load is 64 lanes x 16B = 1KB dense. V layout folds in the
// zero-shuffle key permutation. Attn math identical to R9.

typedef __bf16 bf16;
typedef __bf16 bf16x4 __attribute__((ext_vector_type(4)));
typedef __bf16 bf16x8 __attribute__((ext_vector_type(8)));
typedef float f32x4 __attribute__((ext_vector_type(4)));
typedef unsigned int u32x4 __attribute__((ext_vector_type(4)));

__device__ __forceinline__ f32x4 mfma16(bf16x8 a, bf16x8 b, f32x4 c) {
    return __builtin_amdgcn_mfma_f32_16x16x32_bf16(a, b, c, 0, 0, 0);
}

__device__ __forceinline__ void gload16(const bf16* g, bf16* l) {
    __builtin_amdgcn_global_load_lds(
        (const __attribute__((address_space(1))) unsigned int*)g,
        (__attribute__((address_space(3))) unsigned int*)l, 16, 0, 0);
}

__device__ __forceinline__ unsigned pkbf16(float a, float b) {
    unsigned lo = (unsigned)__builtin_bit_cast(unsigned short, (bf16)a);
    unsigned hi = (unsigned)__builtin_bit_cast(unsigned short, (bf16)b);
    return lo | (hi << 16);
}

// ---------------- fp32 -> bf16 converts ----------------
__global__ __launch_bounds__(256) void f2b_kernel(const float* __restrict__ in,
                                                  bf16* __restrict__ out, int n) {
    int i = (blockIdx.x * 256 + threadIdx.x) * 4;
    if (i >= n) return;
    float4 v = *(const float4*)&in[i];
    bf16x4 o;
    o.x = (bf16)v.x; o.y = (bf16)v.y; o.z = (bf16)v.z; o.w = (bf16)v.w;
    *(bf16x4*)&out[i] = o;
}

__global__ __launch_bounds__(256) void w2b_kernel(
    const float* __restrict__ w0, const float* __restrict__ w1,
    const float* __restrict__ w2, const float* __restrict__ w3,
    bf16* __restrict__ o0, bf16* __restrict__ o1,
    bf16* __restrict__ o2, bf16* __restrict__ o3) {
    int sel = blockIdx.x >> 10;
    const float* in = sel == 0 ? w0 : sel == 1 ? w1 : sel == 2 ? w2 : w3;
    bf16* out = sel == 0 ? o0 : sel == 1 ? o1 : sel == 2 ? o2 : o3;
    int i = ((blockIdx.x & 1023) * 256 + threadIdx.x) * 4;
    float4 v = *(const float4*)&in[i];
    bf16x4 o;
    o.x = (bf16)v.x; o.y = (bf16)v.y; o.z = (bf16)v.z; o.w = (bf16)v.w;
    *(bf16x4*)&out[i] = o;
}

// ---------------- 128x128 bf16 GEMM, global_load_lds staging -------
// C = A[M,K] @ B[N,K]^T.
// MODE 0: bf16 row-major *scale. MODE 1: f32 out + bias.
// MODE 2: V fragment-direct tiled (key-permuted). MODE 3: K fragment-direct tiled.
// Fragment-direct block: per (ktile=seq/64, h): 4096 elems; element (key,hd) at
//   K: ((key>>4)*2 + (hd>>5))*512 + (key&15)*32 + ((hd>>3)&3)*8 + (hd&7)
//   V: ((hd>>4)*2 + ((key>>4)>>1))*512 + (hd&15)*32 + ((key&15)>>2)*8 + ((key>>4)&1)*4 + (key&3)
template <int MODE>
__device__ __forceinline__ void gemm_body(const bf16* __restrict__ A,
                                          const bf16* __restrict__ B,
                                          bf16* __restrict__ Cb,
                                          float* __restrict__ Cf,
                                          const float* __restrict__ bias,
                                          float scale, int N, int K, int row0, int col0) {
    __shared__ alignas(16) bf16 sA[128 * 32];
    __shared__ alignas(16) bf16 sB[128 * 32];
    const int tid  = threadIdx.x;
    const int lane = tid & 63;
    const int wave = tid >> 6;
    const int wrow = (wave >> 1) * 64;
    const int wcol = (wave & 1) * 64;
    const int la = lane & 15, lb = lane >> 4;

    const f32x4 fzero = {0.f, 0.f, 0.f, 0.f};
    f32x4 acc[4][4];
#pragma unroll
    for (int m = 0; m < 4; ++m)
#pragma unroll
        for (int n = 0; n < 4; ++n) acc[m][n] = fzero;

    for (int k0 = 0; k0 < K; k0 += 32) {
#pragma unroll
        for (int i = 0; i < 2; ++i) {
            int idx = i * 256 + tid;
            int r = idx >> 2, s = idx & 3;
            gload16(&A[(size_t)(row0 + r) * K + k0 + s * 8], &sA[idx * 8]);
            gload16(&B[(size_t)(col0 + r) * K + k0 + s * 8], &sB[idx * 8]);
        }
        __syncthreads();
        bf16x8 af[4], bfv[4];
#pragma unroll
        for (int m = 0; m < 4; ++m)
            af[m] = *(const bf16x8*)&sA[(wrow + m * 16 + la) * 32 + lb * 8];
#pragma unroll
        for (int n = 0; n < 4; ++n)
            bfv[n] = *(const bf16x8*)&sB[(wcol + n * 16 + la) * 32 + lb * 8];
#pragma unroll
        for (int m = 0; m < 4; ++m)
#pragma unroll
            for (int n = 0; n < 4; ++n)
                acc[m][n] = mfma16(af[m], bfv[n], acc[m][n]);
        __syncthreads();
    }
#pragma unroll
    for (int m = 0; m < 4; ++m)
#pragma unroll
        for (int n = 0; n < 4; ++n) {
            int col = col0 + wcol + n * 16 + la;
            if (MODE == 2) {
                // V fragment-direct, vectorized: 4 consecutive keys -> consecutive jj
                int hh = col >> 6, hd = col & 63;
                int hc = hd >> 4, lav = hd & 15;
                int sp = row0 + wrow + m * 16 + lb * 4;   // 4-aligned key base
                int ktile = sp >> 6, k = sp & 63;
                int c = k >> 4, q = k & 15;
                size_t addr = (size_t)(ktile * 16 + hh) * 4096 +
                              (size_t)(((hc * 2 + (c >> 1)) * 16 + lav) * 32 +
                                       (q >> 2) * 8 + (c & 1) * 4);
                bf16x4 o4;
#pragma unroll
                for (int r = 0; r < 4; ++r) o4[r] = (bf16)acc[m][n][r];
                *(bf16x4*)&Cb[addr] = o4;
            } else if (MODE == 3) {
                // K fragment-direct: scalar stores (la varies with r)
                int hh = col >> 6, hd = col & 63;
#pragma unroll
                for (int r = 0; r < 4; ++r) {
                    int row = row0 + wrow + m * 16 + lb * 4 + r;
                    int ktile = row >> 6, key = row & 63;
                    size_t addr = (size_t)(ktile * 16 + hh) * 4096 +
                                  (size_t)((((key >> 4) * 2 + (hd >> 5)) * 16 +
                                            (key & 15)) * 32 +
                                           ((hd >> 3) & 3) * 8 + (hd & 7));
                    Cb[addr] = (bf16)acc[m][n][r];
                }
            } else {
#pragma unroll
                for (int r = 0; r < 4; ++r) {
                    int row = row0 + wrow + m * 16 + lb * 4 + r;
                    if (MODE == 1)
                        Cf[(size_t)row * N + col] = acc[m][n][r] + bias[col];
                    else
                        Cb[(size_t)row * N + col] = (bf16)(acc[m][n][r] * scale);
                }
            }
        }
}

__global__ __launch_bounds__(256) void gemm_qkv_kernel(
    const bf16* __restrict__ xb, const bf16* __restrict__ wq,
    const bf16* __restrict__ wk, const bf16* __restrict__ wv,
    bf16* __restrict__ Q, bf16* __restrict__ Kf, bf16* __restrict__ Vf) {
    int z = blockIdx.z;
    if (z == 2) {
        gemm_body<2>(xb, wv, Vf, nullptr, nullptr, 1.f, 1024, 1024,
                     blockIdx.x * 128, blockIdx.y * 128);
    } else if (z == 1) {
        gemm_body<3>(xb, wk, Kf, nullptr, nullptr, 1.f, 1024, 1024,
                     blockIdx.x * 128, blockIdx.y * 128);
    } else {
        gemm_body<0>(xb, wq, Q, nullptr, nullptr, 0.1803368801111204f, 1024, 1024,
                     blockIdx.x * 128, blockIdx.y * 128);
    }
}

__global__ __launch_bounds__(256) void gemm_out_kernel(
    const bf16* __restrict__ att, const bf16* __restrict__ wo,
    float* __restrict__ out, const float* __restrict__ bias) {
    gemm_body<1>(att, wo, nullptr, out, bias, 1.f, 1024, 1024,
                 blockIdx.x * 128, blockIdx.y * 128);
}

// ---------------- flash attention (causal), swapped-QK, fragment-direct K/V ------------
// Q/O: [b*2048+n][h*64+hd] (ld 1024). Kf/Vf: per (ktile=b*32+t, h) 8KB blocks in
// per-lane fragment order; every load = 1KB dense per instruction.
// 4 waves/block, 32 q-rows/wave, KBLK=64. p = exp2(s - 10*log2e), fixed max.
struct KF { bf16x8 f[4][2]; };

__global__ __launch_bounds__(256, 2) void attn_kernel(
    const bf16* __restrict__ Q, const bf16* __restrict__ Kf,
    const bf16* __restrict__ Vf, bf16* __restrict__ O) {
    const int lane = threadIdx.x & 63;
    const int wave = threadIdx.x >> 6;
    const int bid = blockIdx.x;                       // 0..511
    const int bh = (bid & 7) * 4 + ((bid >> 3) & 3);  // XCD-pinned (b,h)
    const int slot = bid >> 5;                        // 0..15
    const int qt = slot < 8 ? slot : 23 - slot;       // long+short pairing
    const int h = bh & 15;
    const int b = bh >> 4;
    const int q0w = qt * 128 + wave * 32;
    const int rowbase = b * 2048;
    const int la = lane & 15, lb = lane >> 4;
    const f32x4 fzero = {0.f, 0.f, 0.f, 0.f};
    const float C = 14.426950408889634f;  // 10 * log2(e)
    const int colbase = h * 64;
    const int lane_off = la * 32 + lb * 8;            // within 512-elem fragment group

    bf16x8 aq[2][2];
#pragma unroll
    for (int mf = 0; mf < 2; ++mf) {
        const bf16* qp = &Q[(size_t)(rowbase + q0w + mf * 16 + la) * 1024 + colbase];
#pragma unroll
        for (int kc = 0; kc < 2; ++kc) aq[mf][kc] = *(const bf16x8*)(qp + kc * 32 + lb * 8);
    }

    bf16x8 bones;
#pragma unroll
    for (int j = 0; j < 8; ++j) bones[j] = (bf16)1.0f;

    f32x4 o[2][4], lacc[2];
#pragma unroll
    for (int mf = 0; mf < 2; ++mf) {
        lacc[mf] = fzero;
#pragma unroll
        for (int hc = 0; hc < 4; ++hc) o[mf][hc] = fzero;
    }

    const int nt = (q0w + 95) >> 6;  // exact causal trip count

    KF ka, kb;
    {
        const bf16* kp = &Kf[(size_t)((b * 32 + 0) * 16 + h) * 4096 + lane_off];
#pragma unroll
        for (int ck = 0; ck < 4; ++ck) {
            ka.f[ck][0] = *(const bf16x8*)(kp + (ck * 2 + 0) * 512);
            ka.f[ck][1] = *(const bf16x8*)(kp + (ck * 2 + 1) * 512);
        }
    }

    auto TILE = [&](int tile, KF& kc, KF& kn, int pref) {
        const int k0 = tile * 64;
        const bool domask = (tile == nt - 1);
        // V loads for this tile (fragment-direct, dense 1KB/instr)
        bf16x8 bv[4][2];
        {
            const bf16* vp = &Vf[(size_t)((b * 32 + tile) * 16 + h) * 4096 + lane_off];
#pragma unroll
            for (int hc = 0; hc < 4; ++hc) {
                bv[hc][0] = *(const bf16x8*)(vp + (hc * 2 + 0) * 512);
                bv[hc][1] = *(const bf16x8*)(vp + (hc * 2 + 1) * 512);
            }
        }
        // K prefetch for next tile
        {
            const bf16* kp = &Kf[(size_t)((b * 32 + pref) * 16 + h) * 4096 + lane_off];
#pragma unroll
            for (int ck = 0; ck < 4; ++ck) {
                kn.f[ck][0] = *(const bf16x8*)(kp + (ck * 2 + 0) * 512);
                kn.f[ck][1] = *(const bf16x8*)(kp + (ck * 2 + 1) * 512);
            }
        }
        // S^T = K @ Q^T : lane holds keys (k0 + ck*16 + lb*4 + r) for q-row (q0w+mf*16+la)
        f32x4 s[2][4];
#pragma unroll
        for (int mf = 0; mf < 2; ++mf)
#pragma unroll
            for (int ck = 0; ck < 4; ++ck) s[mf][ck] = fzero;
#pragma unroll
        for (int ck = 0; ck < 4; ++ck)
#pragma unroll
            for (int mf = 0; mf < 2; ++mf) {
                s[mf][ck] = mfma16(kc.f[ck][0], aq[mf][0], s[mf][ck]);
                s[mf][ck] = mfma16(kc.f[ck][1], aq[mf][1], s[mf][ck]);
            }
        if (domask) {
#pragma unroll
            for (int mf = 0; mf < 2; ++mf) {
                int qrow = q0w + mf * 16 + la;
#pragma unroll
                for (int ck = 0; ck < 4; ++ck)
#pragma unroll
                    for (int r = 0; r < 4; ++r) {
                        int key = k0 + ck * 16 + lb * 4 + r;
                        if (key > qrow) s[mf][ck][r] = -1e30f;
                    }
            }
        }
        // P = exp2(s - C); assemble PV A-frags from OWN lane (no shuffles)
        bf16x8 pa[2][2];
#pragma unroll
        for (int mf = 0; mf < 2; ++mf) {
            unsigned pk[4][2];
#pragma unroll
            for (int ck = 0; ck < 4; ++ck) {
                float p0 = __builtin_amdgcn_exp2f(s[mf][ck][0] - C);
                float p1 = __builtin_amdgcn_exp2f(s[mf][ck][1] - C);
                float p2 = __builtin_amdgcn_exp2f(s[mf][ck][2] - C);
                float p3 = __builtin_amdgcn_exp2f(s[mf][ck][3] - C);
                pk[ck][0] = pkbf16(p0, p1);
                pk[ck][1] = pkbf16(p2, p3);
            }
#pragma unroll
            for (int kc2 = 0; kc2 < 2; ++kc2) {
                u32x4 w;
                w.x = pk[kc2 * 2][0];
                w.y = pk[kc2 * 2][1];
                w.z = pk[kc2 * 2 + 1][0];
                w.w = pk[kc2 * 2 + 1][1];
                pa[mf][kc2] = __builtin_bit_cast(bf16x8, w);
            }
        }
        // PV + l-sum via ones (V layout matches pa's key permutation)
#pragma unroll
        for (int hc = 0; hc < 4; ++hc)
#pragma unroll
            for (int mf = 0; mf < 2; ++mf) {
                o[mf][hc] = mfma16(pa[mf][0], bv[hc][0], o[mf][hc]);
                o[mf][hc] = mfma16(pa[mf][1], bv[hc][1], o[mf][hc]);
            }
#pragma unroll
        for (int mf = 0; mf < 2; ++mf) {
            lacc[mf] = mfma16(pa[mf][0], bones, lacc[mf]);
            lacc[mf] = mfma16(pa[mf][1], bones, lacc[mf]);
        }
    };

    int t = 0;
    for (; t + 2 <= nt; t += 2) {
        TILE(t, ka, kb, t + 1);
        TILE(t + 1, kb, ka, (t + 2 < nt ? t + 2 : nt - 1));
    }
    if (t < nt) TILE(t, ka, kb, nt - 1);

    // epilogue: o row = q-sub lb*4+r, col = hd = hc*16+la
#pragma unroll
    for (int mf = 0; mf < 2; ++mf)
#pragma unroll
        for (int hc = 0; hc < 4; ++hc)
#pragma unroll
            for (int r = 0; r < 4; ++r) {
                int qrow = q0w + mf * 16 + lb * 4 + r;
                O[(size_t)(rowbase + qrow) * 1024 + colbase + hc * 16 + la] =
                    (bf16)(o[mf][hc][r] / lacc[mf][r]);
            }
}

// ---------------- launch ----------------
extern "C" void kernel_launch(void* const* d_in, const int* in_sizes, int n_in,
                              void* d_out, int out_size, void* d_ws, size_t ws_size,
                              hipStream_t stream) {
    const float* x  = (const float*)d_in[0];
    const float* Wq = (const float*)d_in[1];
    const float* Wk = (const float*)d_in[2];
    const float* Wv = (const float*)d_in[3];
    const float* Wo = (const float*)d_in[4];
    const float* bo = (const float*)d_in[5];
    float* out = (float*)d_out;

    char* ws = (char*)d_ws;
    const size_t MB = 1024 * 1024;
    bf16* xb  = (bf16*)(ws + (size_t)0);
    bf16* wqb = (bf16*)(ws + 8 * MB);
    bf16* wkb = (bf16*)(ws + 10 * MB);
    bf16* wvb = (bf16*)(ws + 12 * MB);
    bf16* wob = (bf16*)(ws + 14 * MB);
    bf16* Qb  = (bf16*)(ws + 16 * MB);
    bf16* Kf  = (bf16*)(ws + 24 * MB);   // 128 ktiles x 16 h x 8KB = 16 MB
    bf16* Vf  = (bf16*)(ws + 40 * MB);   // 16 MB
    bf16* Ab  = (bf16*)(ws + 56 * MB);

    f2b_kernel<<<4096, 256, 0, stream>>>(x, xb, 4096 * 1024);
    w2b_kernel<<<4096, 256, 0, stream>>>(Wq, Wk, Wv, Wo, wqb, wkb, wvb, wob);

    gemm_qkv_kernel<<<dim3(32, 8, 3), 256, 0, stream>>>(xb, wqb, wkb, wvb, Qb, Kf, Vf);
    attn_kernel<<<512, 256, 0, stream>>>(Qb, Kf, Vf, Ab);
    gemm_out_kernel<<<dim3(32, 8), 256, 0, stream>>>(Ab, wob, out, bo);
}